// Round 1
// 80.563 us; speedup vs baseline: 1.2631x; 1.2631x over previous
//
#include <hip/hip_runtime.h>
#include <math.h>

#define BB 2
#define NN 384
#define PP 128
#define HH 64
#define EE 32
#define NP 512
#define K1S 136   // w1p LDS stride (bf16): 272B
#define K2S 72    // w2p/tw1p/tw2p stride: 144B

// output layout: upd_q | upd_x | upd_torsions | o  (flat, fp32)
#define X_OFF (BB*NN*4)
#define T_OFF (X_OFF + BB*NN*3)
#define O_OFF (T_OFF + BB*NN*14)

using bf16x8 = __attribute__((ext_vector_type(8))) __bf16;
using f32x4  = __attribute__((ext_vector_type(4))) float;

__device__ __forceinline__ f32x4 MFMA(bf16x8 a, bf16x8 b, f32x4 c) {
  return __builtin_amdgcn_mfma_f32_16x16x32_bf16(a, b, c, 0, 0, 0);
}
// LDS fragment read (element offset into a __bf16 array)
__device__ __forceinline__ bf16x8 LDF(const __bf16* base, int off) {
  return *(const bf16x8*)(base + off);
}
// pack two f32x4 into bf16x8
__device__ __forceinline__ bf16x8 pack8(f32x4 lo, f32x4 hi) {
  bf16x8 r;
  r[0]=(__bf16)lo[0]; r[1]=(__bf16)lo[1]; r[2]=(__bf16)lo[2]; r[3]=(__bf16)lo[3];
  r[4]=(__bf16)hi[0]; r[5]=(__bf16)hi[1]; r[6]=(__bf16)hi[2]; r[7]=(__bf16)hi[3];
  return r;
}
__device__ __forceinline__ bf16x8 pack8v(float4 lo, float4 hi) {
  bf16x8 r;
  r[0]=(__bf16)lo.x; r[1]=(__bf16)lo.y; r[2]=(__bf16)lo.z; r[3]=(__bf16)lo.w;
  r[4]=(__bf16)hi.x; r[5]=(__bf16)hi.y; r[6]=(__bf16)hi.z; r[7]=(__bf16)hi.w;
  return r;
}
// Column permutation: n(t,q) = (t>>1)*32 + (q>>2)*8 + (t&1)*4 + (q&3).
// rowpos(n) = t*16+q, the inverse: which (tile,row) holds output column n.
__device__ __forceinline__ int rowpos(int n) {
  const int t = (n>>5)*2 + ((n>>2)&1);
  const int q = ((n>>3)&3)*4 + (n&3);
  return t*16 + q;
}

// One block = one (b,i) node, 4 waves. Wave w handles edges w*128..w*128+127
// in 8 strips of 16. No barriers in the strip loop: the permuted-output
// swapped-operand MFMA chain keeps each edge's activations lane-local.
// Weight fragments (W1, W2, tw1) are read from LDS *inside* the strip loop
// (per-iteration asm launder defeats LICM) so persistent VGPR demand stays
// under the 128-reg / 4-waves-per-SIMD boundary with zero scratch spill.
__global__ __launch_bounds__(256, 2) void egnn_edge_swapped(
    const float* __restrict__ frames_q, const float* __restrict__ frames_x,
    const float* __restrict__ h, const float* __restrict__ e,
    const int* __restrict__ node_mask,
    const float* __restrict__ pocket_h, const float* __restrict__ pe,
    const float* __restrict__ pocket_q, const float* __restrict__ pocket_x,
    const int* __restrict__ pocket_mask,
    const float* __restrict__ w1, const float* __restrict__ b1,
    const float* __restrict__ w2, const float* __restrict__ b2,
    const float* __restrict__ tw1, const float* __restrict__ tb1,
    const float* __restrict__ tw2, const float* __restrict__ tb2,
    float* __restrict__ msum_ws, float* __restrict__ gdx_ws)
{
  __shared__ __align__(16) __bf16 s_w1p[64*K1S];   // permuted W1^T (k-dim 0..127)
  __shared__ __align__(16) __bf16 s_w2p[64*K2S];   // permuted W2^T
  __shared__ __align__(16) __bf16 s_tw1p[64*K2S];  // permuted tw1^T
  __shared__ __align__(16) __bf16 s_tw2p[16*K2S];  // tw2^T (rows 0..2 = dims)
  __shared__ float s_b2[64], s_tb1[64], s_tb2[4];
  __shared__ float s_msum[64], s_gdx[3];

  const int tid = threadIdx.x;
  const int b = blockIdx.x / NN, i = blockIdx.x % NN;

  // ---- stage permuted weights to LDS (bf16) ----
  for (int idx = tid; idx < 64*128; idx += 256) {
    const int n = idx & 63, k = idx >> 6;
    float v = 0.f;
    if      (k < 64)  v = w1[(64 + k)*64 + n];         // h_j rows
    else if (k < 96)  v = w1[(128 + (k-64))*64 + n];   // e rows
    else if (k < 105) v = w1[(160 + (k-96))*64 + n];   // geom rows (lx,lq,d2,qdot)
    s_w1p[rowpos(n)*K1S + k] = (__bf16)v;              // k==105 overwritten below
  }
  for (int idx = tid; idx < 64*64; idx += 256) {
    const int n = idx & 63, k = idx >> 6;
    s_w2p[rowpos(n)*K2S + k]  = (__bf16)w2[k*64 + n];
    s_tw1p[rowpos(n)*K2S + k] = (__bf16)tw1[k*64 + n];
  }
  for (int idx = tid; idx < 16*64; idx += 256) {
    const int row = idx >> 6, k = idx & 63;
    s_tw2p[row*K2S + k] = (__bf16)((row < 3) ? tw2[k*3 + row] : 0.f);
  }
  if (tid < 64) { s_b2[tid] = b2[tid]; s_tb1[tid] = tb1[tid]; s_msum[tid] = 0.f; }
  if (tid < 3)  { s_tb2[tid] = tb2[tid]; s_gdx[tid] = 0.f; }
  __syncthreads();
  // base_i = b1 + h_i @ W1[0:64] -> const column k=105 (feat[105] = 1.0)
  if (tid < 64) {
    const float* hi = &h[(b*NN + i)*HH];
    float a = b1[tid];
#pragma unroll 8
    for (int c = 0; c < 64; ++c) a = fmaf(hi[c], w1[c*64 + tid], a);
    s_w1p[rowpos(tid)*K1S + 105] = (__bf16)a;
  }
  __syncthreads();

  const int wv = tid >> 6, lane = tid & 63;
  const int l15 = lane & 15, lg = lane >> 4;

  // ---- per-wave register prologue (small stuff only) ----
  bf16x8 tw2f[2];
  tw2f[0] = *(const bf16x8*)&s_tw2p[l15*K2S +  0 + lg*8];
  tw2f[1] = *(const bf16x8*)&s_tw2p[l15*K2S + 32 + lg*8];

  float b2r[16], tb1r[16];
#pragma unroll
  for (int t2 = 0; t2 < 4; ++t2)
#pragma unroll
    for (int r = 0; r < 4; ++r) {
      const int n2 = (t2>>1)*32 + lg*8 + (t2&1)*4 + r;
      b2r[t2*4 + r]  = s_b2[n2];
      tb1r[t2*4 + r] = s_tb1[n2];
    }
  const float tb2r0 = s_tb2[0], tb2r1 = s_tb2[1], tb2r2 = s_tb2[2];

  const int maski = node_mask[b*NN + i];
  const float qi0 = frames_q[(b*NN+i)*4+0], qi1 = frames_q[(b*NN+i)*4+1],
              qi2 = frames_q[(b*NN+i)*4+2], qi3 = frames_q[(b*NN+i)*4+3];
  const float xi0 = frames_x[(b*NN+i)*3+0], xi1 = frames_x[(b*NN+i)*3+1],
              xi2 = frames_x[(b*NN+i)*3+2];

  float msacc[16];
#pragma unroll
  for (int v = 0; v < 16; ++v) msacc[v] = 0.f;
  float gx0 = 0.f, gx1 = 0.f, gx2 = 0.f;

  const int o1base = l15*K1S + lg*8;   // W1 frag base (element offset)
  const int o2base = l15*K2S + lg*8;   // W2 / tw1 frag base

#pragma unroll 2
  for (int s = 0; s < 8; ++s) {
    // per-iteration launder: keeps the weight-fragment ds_reads inside the
    // loop (LICM would otherwise hoist 24 bf16x8 frags back into registers
    // and blow the VGPR budget -> scratch spills)
    int o1 = o1base; asm volatile("" : "+v"(o1));
    int o2 = o2base; asm volatile("" : "+v"(o2));

    const int jbase = wv*128 + s*16;
    const int j = jbase + l15;
    const bool isn = (jbase < NN);      // uniform per strip
    const float *hj, *ej, *qj, *xj;
    int mj;
    if (isn) {
      hj = &h[(b*NN + j)*HH];
      ej = &e[((b*NN + i)*NN + j)*EE];
      qj = &frames_q[(b*NN + j)*4];
      xj = &frames_x[(b*NN + j)*3];
      mj = (node_mask[b*NN + j] != 0) && (j != i);
    } else {
      const int jp = j - NN;
      hj = &pocket_h[(b*PP + jp)*HH];
      ej = &pe[((b*NN + i)*PP + jp)*EE];
      qj = &pocket_q[(b*PP + jp)*4];
      xj = &pocket_x[(b*PP + jp)*3];
      mj = (pocket_mask[b*PP + jp] != 0);
    }
    const float mask_f = (maski && mj) ? 1.f : 0.f;

    const float4 h0 = *(const float4*)&hj[lg*8];
    const float4 h1 = *(const float4*)&hj[lg*8 + 4];
    const float4 h2 = *(const float4*)&hj[32 + lg*8];
    const float4 h3 = *(const float4*)&hj[32 + lg*8 + 4];
    const float4 e0 = *(const float4*)&ej[lg*8];
    const float4 e1 = *(const float4*)&ej[lg*8 + 4];
    const float qj0 = qj[0], qj1 = qj[1], qj2 = qj[2], qj3 = qj[3];
    const float xj0 = xj[0], xj1 = xj[1], xj2 = xj[2];

    // geometry for edge l15 (computed redundantly by the 4 lanes sharing l15)
    const float v0 = xi0 - xj0, v1 = xi1 - xj1, v2 = xi2 - xj2;
    const float d2 = v0*v0 + v1*v1 + v2*v2;
    const float qdot = fabsf(qi0*qj0 + qi1*qj1 + qi2*qj2 + qi3*qj3);
    const float cw = qj0, cx = -qj1, cy = -qj2, cz = -qj3;
    const float t0 = 2.f*(cy*v2 - cz*v1);
    const float t1 = 2.f*(cz*v0 - cx*v2);
    const float t2 = 2.f*(cx*v1 - cy*v0);
    const float lx0 = v0 + cw*t0 + (cy*t2 - cz*t1);
    const float lx1 = v1 + cw*t1 + (cz*t0 - cx*t2);
    const float lx2 = v2 + cw*t2 + (cx*t1 - cy*t0);
    const float lq0 = cw*qi0 - cx*qi1 - cy*qi2 - cz*qi3;
    const float lq1 = cw*qi1 + cx*qi0 + cy*qi3 - cz*qi2;
    const float lq2 = cw*qi2 - cx*qi3 + cy*qi0 + cz*qi1;
    const float lq3 = cw*qi3 + cx*qi2 - cy*qi1 + cz*qi0;

    // B-fragments of L1: feat^T, k-slices of 32
    const bf16x8 bf0 = pack8v(h0, h1);
    const bf16x8 bf1 = pack8v(h2, h3);
    const bf16x8 bf2 = pack8v(e0, e1);
    float g_[8];
    if (lg == 0) { g_[0]=lx0; g_[1]=lx1; g_[2]=lx2; g_[3]=lq0; g_[4]=lq1; g_[5]=lq2; g_[6]=lq3; g_[7]=d2; }
    else if (lg == 1) { g_[0]=qdot; g_[1]=1.f; g_[2]=0.f; g_[3]=0.f; g_[4]=0.f; g_[5]=0.f; g_[6]=0.f; g_[7]=0.f; }
    else { g_[0]=0.f; g_[1]=0.f; g_[2]=0.f; g_[3]=0.f; g_[4]=0.f; g_[5]=0.f; g_[6]=0.f; g_[7]=0.f; }
    bf16x8 bf3;
    bf3[0]=(__bf16)g_[0]; bf3[1]=(__bf16)g_[1]; bf3[2]=(__bf16)g_[2]; bf3[3]=(__bf16)g_[3];
    bf3[4]=(__bf16)g_[4]; bf3[5]=(__bf16)g_[5]; bf3[6]=(__bf16)g_[6]; bf3[7]=(__bf16)g_[7];

    const f32x4 zero4 = {0.f, 0.f, 0.f, 0.f};
    // ---- L1: hidden^T tiles (output cols permuted by n(t,q)) ----
    // A-fragments streamed from LDS (ds_read_b128, const offsets fold into
    // the 16-bit ds immediate). Pattern is the uniform 8-lanes-per-bank-group
    // layout -> conflict-free at b128 throughput.
    f32x4 a0 = MFMA(LDF(s_w1p, o1 + 0*16*K1S +  0), bf0, zero4);
    a0 = MFMA(LDF(s_w1p, o1 + 0*16*K1S + 32), bf1, a0);
    a0 = MFMA(LDF(s_w1p, o1 + 0*16*K1S + 64), bf2, a0);
    a0 = MFMA(LDF(s_w1p, o1 + 0*16*K1S + 96), bf3, a0);
    f32x4 a1 = MFMA(LDF(s_w1p, o1 + 1*16*K1S +  0), bf0, zero4);
    a1 = MFMA(LDF(s_w1p, o1 + 1*16*K1S + 32), bf1, a1);
    a1 = MFMA(LDF(s_w1p, o1 + 1*16*K1S + 64), bf2, a1);
    a1 = MFMA(LDF(s_w1p, o1 + 1*16*K1S + 96), bf3, a1);
#pragma unroll
    for (int r = 0; r < 4; ++r) { a0[r] = fmaxf(a0[r], 0.f); a1[r] = fmaxf(a1[r], 0.f); }
    const bf16x8 hb0 = pack8(a0, a1);
    f32x4 a2 = MFMA(LDF(s_w1p, o1 + 2*16*K1S +  0), bf0, zero4);
    a2 = MFMA(LDF(s_w1p, o1 + 2*16*K1S + 32), bf1, a2);
    a2 = MFMA(LDF(s_w1p, o1 + 2*16*K1S + 64), bf2, a2);
    a2 = MFMA(LDF(s_w1p, o1 + 2*16*K1S + 96), bf3, a2);
    f32x4 a3 = MFMA(LDF(s_w1p, o1 + 3*16*K1S +  0), bf0, zero4);
    a3 = MFMA(LDF(s_w1p, o1 + 3*16*K1S + 32), bf1, a3);
    a3 = MFMA(LDF(s_w1p, o1 + 3*16*K1S + 64), bf2, a3);
    a3 = MFMA(LDF(s_w1p, o1 + 3*16*K1S + 96), bf3, a3);
#pragma unroll
    for (int r = 0; r < 4; ++r) { a2[r] = fmaxf(a2[r], 0.f); a3[r] = fmaxf(a3[r], 0.f); }
    const bf16x8 hb1 = pack8(a2, a3);

    // ---- L2: m^T tiles ----
    f32x4 c0 = MFMA(LDF(s_w2p, o2 + 0*16*K2S +  0), hb0, zero4);
    c0 = MFMA(LDF(s_w2p, o2 + 0*16*K2S + 32), hb1, c0);
    f32x4 c1 = MFMA(LDF(s_w2p, o2 + 1*16*K2S +  0), hb0, zero4);
    c1 = MFMA(LDF(s_w2p, o2 + 1*16*K2S + 32), hb1, c1);
#pragma unroll
    for (int r = 0; r < 4; ++r) {
      c0[r] = (c0[r] + b2r[0*4+r]) * mask_f;  msacc[0*4+r] += c0[r];
      c1[r] = (c1[r] + b2r[1*4+r]) * mask_f;  msacc[1*4+r] += c1[r];
    }
    const bf16x8 mb0 = pack8(c0, c1);
    f32x4 c2 = MFMA(LDF(s_w2p, o2 + 2*16*K2S +  0), hb0, zero4);
    c2 = MFMA(LDF(s_w2p, o2 + 2*16*K2S + 32), hb1, c2);
    f32x4 c3 = MFMA(LDF(s_w2p, o2 + 3*16*K2S +  0), hb0, zero4);
    c3 = MFMA(LDF(s_w2p, o2 + 3*16*K2S + 32), hb1, c3);
#pragma unroll
    for (int r = 0; r < 4; ++r) {
      c2[r] = (c2[r] + b2r[2*4+r]) * mask_f;  msacc[2*4+r] += c2[r];
      c3[r] = (c3[r] + b2r[3*4+r]) * mask_f;  msacc[3*4+r] += c3[r];
    }
    const bf16x8 mb1 = pack8(c2, c3);

    // ---- tr1: th^T tiles (tw1 A-frags from LDS) ----
    f32x4 d0 = MFMA(LDF(s_tw1p, o2 + 0*16*K2S +  0), mb0, zero4);
    d0 = MFMA(LDF(s_tw1p, o2 + 0*16*K2S + 32), mb1, d0);
    f32x4 d1 = MFMA(LDF(s_tw1p, o2 + 1*16*K2S +  0), mb0, zero4);
    d1 = MFMA(LDF(s_tw1p, o2 + 1*16*K2S + 32), mb1, d1);
#pragma unroll
    for (int r = 0; r < 4; ++r) {
      d0[r] = fmaxf(d0[r] + tb1r[0*4+r], 0.f);
      d1[r] = fmaxf(d1[r] + tb1r[1*4+r], 0.f);
    }
    const bf16x8 thb0 = pack8(d0, d1);
    f32x4 d2f = MFMA(LDF(s_tw1p, o2 + 2*16*K2S +  0), mb0, zero4);
    d2f = MFMA(LDF(s_tw1p, o2 + 2*16*K2S + 32), mb1, d2f);
    f32x4 d3 = MFMA(LDF(s_tw1p, o2 + 3*16*K2S +  0), mb0, zero4);
    d3 = MFMA(LDF(s_tw1p, o2 + 3*16*K2S + 32), mb1, d3);
#pragma unroll
    for (int r = 0; r < 4; ++r) {
      d2f[r] = fmaxf(d2f[r] + tb1r[2*4+r], 0.f);
      d3[r]  = fmaxf(d3[r]  + tb1r[3*4+r], 0.f);
    }
    const bf16x8 thb1 = pack8(d2f, d3);

    // ---- dx: 2 MFMAs with tw2^T (rows 0..2 = dims) ----
    f32x4 dacc = MFMA(tw2f[0], thb0, zero4);
    dacc = MFMA(tw2f[1], thb1, dacc);

    if (lg == 0) {
      const float dx0 = (dacc[0] + tb2r0) * mask_f;
      const float dx1 = (dacc[1] + tb2r1) * mask_f;
      const float dx2 = (dacc[2] + tb2r2) * mask_f;
      const float inv = 1.f / fmaxf(sqrtf(qj0*qj0 + qj1*qj1 + qj2*qj2 + qj3*qj3), 1e-12f);
      const float w = qj0*inv, ux = qj1*inv, uy = qj2*inv, uz = qj3*inv;
      const float r0 = 2.f*(uy*dx2 - uz*dx1);
      const float r1 = 2.f*(uz*dx0 - ux*dx2);
      const float r2 = 2.f*(ux*dx1 - uy*dx0);
      gx0 += dx0 + w*r0 + (uy*r2 - uz*r1);
      gx1 += dx1 + w*r1 + (uz*r0 - ux*r2);
      gx2 += dx2 + w*r2 + (ux*r1 - uy*r0);
    }
  }

  // ---- epilogue: msum (reduce over the 16 l15 lanes), gdx ----
#pragma unroll
  for (int v = 0; v < 16; ++v) {
    float x = msacc[v];
    x += __shfl_xor(x, 1); x += __shfl_xor(x, 2);
    x += __shfl_xor(x, 4); x += __shfl_xor(x, 8);
    if (l15 == 0) {
      const int n2 = (v>>3)*32 + lg*8 + ((v>>2)&1)*4 + (v&3);
      atomicAdd(&s_msum[n2], x);
    }
  }
  {
    float v0 = (lg == 0) ? gx0 : 0.f;
    float v1 = (lg == 0) ? gx1 : 0.f;
    float v2 = (lg == 0) ? gx2 : 0.f;
#pragma unroll
    for (int sft = 1; sft < 64; sft <<= 1) {
      v0 += __shfl_xor(v0, sft); v1 += __shfl_xor(v1, sft); v2 += __shfl_xor(v2, sft);
    }
    if (lane == 0) { atomicAdd(&s_gdx[0], v0); atomicAdd(&s_gdx[1], v1); atomicAdd(&s_gdx[2], v2); }
  }
  __syncthreads();
  if (tid < 64) msum_ws[(b*NN + i)*64 + tid] = s_msum[tid];
  if (tid >= 64 && tid < 67) gdx_ws[(b*NN + i)*3 + (tid - 64)] = s_gdx[tid - 64];
}

// One block (1 wave) per (b, i): o, dq->upd_q, upd_x, torsions.
__global__ __launch_bounds__(64) void egnn_node_kernel(
    const float* __restrict__ frames_q, const float* __restrict__ frames_x,
    const float* __restrict__ h,
    const int* __restrict__ node_mask, const int* __restrict__ pocket_mask,
    const float* __restrict__ fw1, const float* __restrict__ fb1,
    const float* __restrict__ fw2, const float* __restrict__ fb2,
    const float* __restrict__ qw1, const float* __restrict__ qb1,
    const float* __restrict__ qw2, const float* __restrict__ qb2,
    const float* __restrict__ tow1, const float* __restrict__ tob1,
    const float* __restrict__ tow2, const float* __restrict__ tob2,
    const float* __restrict__ msum_ws, const float* __restrict__ gdx_ws,
    float* __restrict__ out)
{
  const int t  = threadIdx.x;
  const int bi = blockIdx.x;
  const int b = bi / NN, i = bi % NN;
  __shared__ float s_h[64], s_ms[64], s_hid[64], s_tmp[16];

  s_h[t]  = h[(b*NN+i)*HH + t];
  s_ms[t] = msum_ws[(b*NN+i)*64 + t];

  int cnt = 0;
  for (int k = t; k < NN; k += 64) cnt += (node_mask[b*NN+k] != 0);
  for (int k = t; k < PP; k += 64) cnt += (pocket_mask[b*PP+k] != 0);
  cnt += __shfl_xor(cnt,1); cnt += __shfl_xor(cnt,2); cnt += __shfl_xor(cnt,4);
  cnt += __shfl_xor(cnt,8); cnt += __shfl_xor(cnt,16); cnt += __shfl_xor(cnt,32);
  const float n_nb = (float)(cnt - 1);

  __syncthreads();
  float a = fb1[t];
  for (int k = 0; k < 64; ++k) a = fmaf(s_h[k],  fw1[k*64 + t], a);
  for (int k = 0; k < 64; ++k) a = fmaf(s_ms[k], fw1[(64+k)*64 + t], a);
  s_hid[t] = fmaxf(a, 0.f);
  __syncthreads();
  float ov = fb2[t];
  for (int k = 0; k < 64; ++k) ov = fmaf(s_hid[k], fw2[k*64 + t], ov);
  out[O_OFF + (b*NN+i)*64 + t] = ov;

  __syncthreads();
  float aq = qb1[t];
  for (int k = 0; k < 64; ++k) aq = fmaf(s_ms[k], qw1[k*64 + t], aq);
  s_hid[t] = fmaxf(aq, 0.f);
  __syncthreads();
  if (t < 4) {
    float d = qb2[t];
    for (int k = 0; k < 64; ++k) d = fmaf(s_hid[k], qw2[k*4 + t], d);
    s_tmp[t] = d;
  }
  __syncthreads();
  if (t == 0) {
    const int mi = node_mask[b*NN+i];
    float d0,d1,d2,d3;
    if (mi) { d0=s_tmp[0]; d1=s_tmp[1]; d2=s_tmp[2]; d3=s_tmp[3]; }
    else    { d0=1.f; d1=0.f; d2=0.f; d3=0.f; }
    float nrm = fmaxf(sqrtf(d0*d0+d1*d1+d2*d2+d3*d3), 1e-12f);
    d0/=nrm; d1/=nrm; d2/=nrm; d3/=nrm;
    const float q0=frames_q[(b*NN+i)*4+0], q1=frames_q[(b*NN+i)*4+1],
                q2=frames_q[(b*NN+i)*4+2], q3=frames_q[(b*NN+i)*4+3];
    float u0 = q0*d0 - q1*d1 - q2*d2 - q3*d3;
    float u1 = q0*d1 + q1*d0 + q2*d3 - q3*d2;
    float u2 = q0*d2 - q1*d3 + q2*d0 + q3*d1;
    float u3 = q0*d3 + q1*d2 - q2*d1 + q3*d0;
    if (!mi) { u0=1.f; u1=0.f; u2=0.f; u3=0.f; }
    float nrm2 = fmaxf(sqrtf(u0*u0+u1*u1+u2*u2+u3*u3), 1e-12f);
    out[(b*NN+i)*4+0]=u0/nrm2; out[(b*NN+i)*4+1]=u1/nrm2;
    out[(b*NN+i)*4+2]=u2/nrm2; out[(b*NN+i)*4+3]=u3/nrm2;
  }
  if (t < 3) {
    out[X_OFF + (b*NN+i)*3 + t] = frames_x[(b*NN+i)*3+t] + gdx_ws[(b*NN+i)*3+t] / n_nb;
  }

  __syncthreads();
  float at = tob1[t];
  for (int k = 0; k < 64; ++k) at = fmaf(s_ms[k], tow1[k*64 + t], at);
  s_hid[t] = fmaxf(at, 0.f);
  __syncthreads();
  if (t < 14) {
    float v = tob2[t];
    for (int k = 0; k < 64; ++k) v = fmaf(s_hid[k], tow2[k*14 + t], v);
    s_tmp[t] = v;
  }
  __syncthreads();
  if (t < 14) {
    const int p = t & ~1;
    const float a0 = s_tmp[p], a1 = s_tmp[p+1];
    const float nrm = fmaxf(sqrtf(a0*a0 + a1*a1), 1e-12f);
    out[T_OFF + (b*NN+i)*14 + t] = s_tmp[t] / nrm;
  }
}

extern "C" void kernel_launch(void* const* d_in, const int* in_sizes, int n_in,
                              void* d_out, int out_size, void* d_ws, size_t ws_size,
                              hipStream_t stream) {
  const float* frames_q    = (const float*)d_in[0];
  const float* frames_x    = (const float*)d_in[1];
  const float* h           = (const float*)d_in[3];
  const float* e           = (const float*)d_in[4];
  const int*   node_mask   = (const int*)d_in[5];
  const float* pocket_h    = (const float*)d_in[6];
  const float* pocket_e    = (const float*)d_in[7];
  const float* pocket_q    = (const float*)d_in[8];
  const float* pocket_x    = (const float*)d_in[9];
  const int*   pocket_mask = (const int*)d_in[10];
  const float* msg_w1 = (const float*)d_in[11];
  const float* msg_b1 = (const float*)d_in[12];
  const float* msg_w2 = (const float*)d_in[13];
  const float* msg_b2 = (const float*)d_in[14];
  const float* feat_w1 = (const float*)d_in[15];
  const float* feat_b1 = (const float*)d_in[16];
  const float* feat_w2 = (const float*)d_in[17];
  const float* feat_b2 = (const float*)d_in[18];
  const float* tr_w1 = (const float*)d_in[19];
  const float* tr_b1 = (const float*)d_in[20];
  const float* tr_w2 = (const float*)d_in[21];
  const float* tr_b2 = (const float*)d_in[22];
  const float* qu_w1 = (const float*)d_in[23];
  const float* qu_b1 = (const float*)d_in[24];
  const float* qu_w2 = (const float*)d_in[25];
  const float* qu_b2 = (const float*)d_in[26];
  const float* to_w1 = (const float*)d_in[27];
  const float* to_b1 = (const float*)d_in[28];
  const float* to_w2 = (const float*)d_in[29];
  const float* to_b2 = (const float*)d_in[30];

  float* out = (float*)d_out;
  float* msum_ws = (float*)d_ws;                 // B*N*64 floats
  float* gdx_ws  = msum_ws + BB*NN*64;           // B*N*3 floats

  egnn_edge_swapped<<<dim3(BB*NN), dim3(256), 0, stream>>>(
      frames_q, frames_x, h, e, node_mask,
      pocket_h, pocket_e, pocket_q, pocket_x, pocket_mask,
      msg_w1, msg_b1, msg_w2, msg_b2,
      tr_w1, tr_b1, tr_w2, tr_b2,
      msum_ws, gdx_ws);

  egnn_node_kernel<<<dim3(BB*NN), dim3(64), 0, stream>>>(
      frames_q, frames_x, h, node_mask, pocket_mask,
      feat_w1, feat_b1, feat_w2, feat_b2,
      qu_w1, qu_b1, qu_w2, qu_b2,
      to_w1, to_b1, to_w2, to_b2,
      msum_ws, gdx_ws, out);
}

// Round 2
// 71.905 us; speedup vs baseline: 1.4152x; 1.1204x over previous
//
#include <hip/hip_runtime.h>
#include <math.h>

#define BB 2
#define NN 384
#define PP 128
#define HH 64
#define EE 32
#define NP 512
#define K1S 136   // w1p LDS stride (bf16): 272B
#define K2S 72    // w2p/tw1p/tw2p stride: 144B

// output layout: upd_q | upd_x | upd_torsions | o  (flat, fp32)
#define X_OFF (BB*NN*4)
#define T_OFF (X_OFF + BB*NN*3)
#define O_OFF (T_OFF + BB*NN*14)

using bf16x8 = __attribute__((ext_vector_type(8))) __bf16;
using f32x4  = __attribute__((ext_vector_type(4))) float;

__device__ __forceinline__ f32x4 MFMA(bf16x8 a, bf16x8 b, f32x4 c) {
  return __builtin_amdgcn_mfma_f32_16x16x32_bf16(a, b, c, 0, 0, 0);
}
// LDS fragment read (element offset into a __bf16 array)
__device__ __forceinline__ bf16x8 LDF(const __bf16* base, int off) {
  return *(const bf16x8*)(base + off);
}
// pack two f32x4 into bf16x8
__device__ __forceinline__ bf16x8 pack8(f32x4 lo, f32x4 hi) {
  bf16x8 r;
  r[0]=(__bf16)lo[0]; r[1]=(__bf16)lo[1]; r[2]=(__bf16)lo[2]; r[3]=(__bf16)lo[3];
  r[4]=(__bf16)hi[0]; r[5]=(__bf16)hi[1]; r[6]=(__bf16)hi[2]; r[7]=(__bf16)hi[3];
  return r;
}
__device__ __forceinline__ bf16x8 pack8v(float4 lo, float4 hi) {
  bf16x8 r;
  r[0]=(__bf16)lo.x; r[1]=(__bf16)lo.y; r[2]=(__bf16)lo.z; r[3]=(__bf16)lo.w;
  r[4]=(__bf16)hi.x; r[5]=(__bf16)hi.y; r[6]=(__bf16)hi.z; r[7]=(__bf16)hi.w;
  return r;
}
// Column permutation: n(t,q) = (t>>1)*32 + (q>>2)*8 + (t&1)*4 + (q&3).
// rowpos(n) = t*16+q, the inverse: which (tile,row) holds output column n.
__device__ __forceinline__ int rowpos(int n) {
  const int t = (n>>5)*2 + ((n>>2)&1);
  const int q = ((n>>3)&3)*4 + (n&3);
  return t*16 + q;
}

// One block = one (b,i) node, 8 waves x 512 threads. Wave w handles edges
// w*64..w*64+63 in 4 strips of 16. Per-edge geometry/mask/qn precomputed by a
// prologue pass (1 thread per j) into LDS so the strip loop is only
// {h/e float4 loads -> pack -> MFMA chain with laundered LDS weight frags}.
__global__ __launch_bounds__(512, 4) void egnn_edge_swapped(
    const float* __restrict__ frames_q, const float* __restrict__ frames_x,
    const float* __restrict__ h, const float* __restrict__ e,
    const int* __restrict__ node_mask,
    const float* __restrict__ pocket_h, const float* __restrict__ pe,
    const float* __restrict__ pocket_q, const float* __restrict__ pocket_x,
    const int* __restrict__ pocket_mask,
    const float* __restrict__ w1, const float* __restrict__ b1,
    const float* __restrict__ w2, const float* __restrict__ b2,
    const float* __restrict__ tw1, const float* __restrict__ tb1,
    const float* __restrict__ tw2, const float* __restrict__ tb2,
    float* __restrict__ msum_ws, float* __restrict__ gdx_ws)
{
  __shared__ __align__(16) __bf16 s_w1p[64*K1S];   // permuted W1^T (k-dim 0..127)
  __shared__ __align__(16) __bf16 s_w2p[64*K2S];   // permuted W2^T
  __shared__ __align__(16) __bf16 s_tw1p[64*K2S];  // permuted tw1^T
  __shared__ __align__(16) __bf16 s_tw2p[16*K2S];  // tw2^T (rows 0..2 = dims)
  __shared__ __align__(16) __bf16 s_geo[NP*16 + 8]; // per-edge bf3 frag (+zero slot)
  __shared__ __align__(16) float s_qn[NP*4];       // normalized q_all
  __shared__ float s_maskf[NP];
  __shared__ float s_b2[64], s_tb1[64], s_tb2[4];
  __shared__ float s_msum[64], s_gdx[3];

  const int tid = threadIdx.x;
  const int b = blockIdx.x / NN, i = blockIdx.x % NN;

  // ---- stage permuted weights to LDS (bf16) ----
  for (int idx = tid; idx < 64*128; idx += 512) {
    const int n = idx & 63, k = idx >> 6;
    float v = 0.f;
    if      (k < 64)  v = w1[(64 + k)*64 + n];         // h_j rows
    else if (k < 96)  v = w1[(128 + (k-64))*64 + n];   // e rows
    else if (k < 105) v = w1[(160 + (k-96))*64 + n];   // geom rows (lx,lq,d2,qdot)
    s_w1p[rowpos(n)*K1S + k] = (__bf16)v;              // k==105 overwritten below
  }
  for (int idx = tid; idx < 64*64; idx += 512) {
    const int n = idx & 63, k = idx >> 6;
    s_w2p[rowpos(n)*K2S + k]  = (__bf16)w2[k*64 + n];
    s_tw1p[rowpos(n)*K2S + k] = (__bf16)tw1[k*64 + n];
  }
  for (int idx = tid; idx < 16*64; idx += 512) {
    const int row = idx >> 6, k = idx & 63;
    s_tw2p[row*K2S + k] = (__bf16)((row < 3) ? tw2[k*3 + row] : 0.f);
  }
  if (tid < 64) { s_b2[tid] = b2[tid]; s_tb1[tid] = tb1[tid]; s_msum[tid] = 0.f; }
  if (tid < 8)  s_geo[NP*16 + tid] = (__bf16)0.f;      // zero slot for lg>=2
  if (tid < 3)  { s_tb2[tid] = tb2[tid]; s_gdx[tid] = 0.f; }
  __syncthreads();

  // base_i = b1 + h_i @ W1[0:64] -> const column k=105 (feat[105] = 1.0)
  if (tid < 64) {
    const float* hi = &h[(b*NN + i)*HH];
    float a = b1[tid];
#pragma unroll 8
    for (int c = 0; c < 64; ++c) a = fmaf(hi[c], w1[c*64 + tid], a);
    s_w1p[rowpos(tid)*K1S + 105] = (__bf16)a;
  }

  // ---- per-edge geometry precompute: one thread per j ----
  {
    const int j = tid;   // 512 threads == NP edges
    const int maski = node_mask[b*NN + i];
    const float qi0 = frames_q[(b*NN+i)*4+0], qi1 = frames_q[(b*NN+i)*4+1],
                qi2 = frames_q[(b*NN+i)*4+2], qi3 = frames_q[(b*NN+i)*4+3];
    const float xi0 = frames_x[(b*NN+i)*3+0], xi1 = frames_x[(b*NN+i)*3+1],
                xi2 = frames_x[(b*NN+i)*3+2];
    float qj0,qj1,qj2,qj3, xj0,xj1,xj2; int mj;
    if (j < NN) {
      const float4 q4 = *(const float4*)&frames_q[(b*NN+j)*4];
      qj0=q4.x; qj1=q4.y; qj2=q4.z; qj3=q4.w;
      xj0=frames_x[(b*NN+j)*3+0]; xj1=frames_x[(b*NN+j)*3+1]; xj2=frames_x[(b*NN+j)*3+2];
      mj = (node_mask[b*NN+j] != 0) && (j != i);
    } else {
      const int jp = j - NN;
      const float4 q4 = *(const float4*)&pocket_q[(b*PP+jp)*4];
      qj0=q4.x; qj1=q4.y; qj2=q4.z; qj3=q4.w;
      xj0=pocket_x[(b*PP+jp)*3+0]; xj1=pocket_x[(b*PP+jp)*3+1]; xj2=pocket_x[(b*PP+jp)*3+2];
      mj = (pocket_mask[b*PP+jp] != 0);
    }
    const float v0 = xi0 - xj0, v1 = xi1 - xj1, v2 = xi2 - xj2;
    const float d2 = v0*v0 + v1*v1 + v2*v2;
    const float qdot = fabsf(qi0*qj0 + qi1*qj1 + qi2*qj2 + qi3*qj3);
    const float cw = qj0, cx = -qj1, cy = -qj2, cz = -qj3;
    const float t0 = 2.f*(cy*v2 - cz*v1);
    const float t1 = 2.f*(cz*v0 - cx*v2);
    const float t2 = 2.f*(cx*v1 - cy*v0);
    const float lx0 = v0 + cw*t0 + (cy*t2 - cz*t1);
    const float lx1 = v1 + cw*t1 + (cz*t0 - cx*t2);
    const float lx2 = v2 + cw*t2 + (cx*t1 - cy*t0);
    const float lq0 = cw*qi0 - cx*qi1 - cy*qi2 - cz*qi3;
    const float lq1 = cw*qi1 + cx*qi0 + cy*qi3 - cz*qi2;
    const float lq2 = cw*qi2 - cx*qi3 + cy*qi0 + cz*qi1;
    const float lq3 = cw*qi3 + cx*qi2 - cy*qi1 + cz*qi0;
    __bf16* g = &s_geo[j*16];
    g[0]=(__bf16)lx0; g[1]=(__bf16)lx1; g[2]=(__bf16)lx2; g[3]=(__bf16)lq0;
    g[4]=(__bf16)lq1; g[5]=(__bf16)lq2; g[6]=(__bf16)lq3; g[7]=(__bf16)d2;
    g[8]=(__bf16)qdot; g[9]=(__bf16)1.f;
    g[10]=(__bf16)0.f; g[11]=(__bf16)0.f; g[12]=(__bf16)0.f;
    g[13]=(__bf16)0.f; g[14]=(__bf16)0.f; g[15]=(__bf16)0.f;
    s_maskf[j] = (maski && mj) ? 1.f : 0.f;
    const float inv = 1.f / fmaxf(sqrtf(qj0*qj0 + qj1*qj1 + qj2*qj2 + qj3*qj3), 1e-12f);
    float4* qn = (float4*)&s_qn[j*4];
    *qn = make_float4(qj0*inv, qj1*inv, qj2*inv, qj3*inv);
  }
  __syncthreads();

  const int wv = tid >> 6, lane = tid & 63;
  const int l15 = lane & 15, lg = lane >> 4;

  // ---- per-wave register prologue (small stuff only) ----
  bf16x8 tw2f[2];
  tw2f[0] = *(const bf16x8*)&s_tw2p[l15*K2S +  0 + lg*8];
  tw2f[1] = *(const bf16x8*)&s_tw2p[l15*K2S + 32 + lg*8];

  float b2r[16], tb1r[16];
#pragma unroll
  for (int t2 = 0; t2 < 4; ++t2)
#pragma unroll
    for (int r = 0; r < 4; ++r) {
      const int n2 = (t2>>1)*32 + lg*8 + (t2&1)*4 + r;
      b2r[t2*4 + r]  = s_b2[n2];
      tb1r[t2*4 + r] = s_tb1[n2];
    }
  const float tb2r0 = s_tb2[0], tb2r1 = s_tb2[1], tb2r2 = s_tb2[2];

  float msacc[16];
#pragma unroll
  for (int v = 0; v < 16; ++v) msacc[v] = 0.f;
  float gx0 = 0.f, gx1 = 0.f, gx2 = 0.f;

  const int o1base = l15*K1S + lg*8;   // W1 frag base (element offset)
  const int o2base = l15*K2S + lg*8;   // W2 / tw1 frag base

#pragma unroll 2
  for (int s = 0; s < 4; ++s) {
    // per-iteration launder: keeps the weight-fragment ds_reads inside the
    // loop (LICM would otherwise hoist 24 bf16x8 frags back into registers
    // and blow the VGPR budget -> scratch spills)
    int o1 = o1base; asm volatile("" : "+v"(o1));
    int o2 = o2base; asm volatile("" : "+v"(o2));

    const int jbase = wv*64 + s*16;
    const int j = jbase + l15;
    const bool isn = (jbase < NN);      // uniform per strip
    const float *hj, *ej;
    if (isn) {
      hj = &h[(b*NN + j)*HH];
      ej = &e[((b*NN + i)*NN + j)*EE];
    } else {
      const int jp = j - NN;
      hj = &pocket_h[(b*PP + jp)*HH];
      ej = &pe[((b*NN + i)*PP + jp)*EE];
    }
    const float mask_f = s_maskf[j];

    const float4 h0 = *(const float4*)&hj[lg*8];
    const float4 h1 = *(const float4*)&hj[lg*8 + 4];
    const float4 h2 = *(const float4*)&hj[32 + lg*8];
    const float4 h3 = *(const float4*)&hj[32 + lg*8 + 4];
    const float4 e0 = *(const float4*)&ej[lg*8];
    const float4 e1 = *(const float4*)&ej[lg*8 + 4];

    // B-fragments of L1: feat^T, k-slices of 32
    const bf16x8 bf0 = pack8v(h0, h1);
    const bf16x8 bf1 = pack8v(h2, h3);
    const bf16x8 bf2 = pack8v(e0, e1);
    // geometry fragment: precomputed; lg>=2 lanes read the shared zero slot
    const bf16x8 bf3 = *(const bf16x8*)&s_geo[(lg < 2) ? (j*16 + lg*8) : NP*16];

    const f32x4 zero4 = {0.f, 0.f, 0.f, 0.f};
    // ---- L1: hidden^T tiles (output cols permuted by n(t,q)) ----
    f32x4 a0 = MFMA(LDF(s_w1p, o1 + 0*16*K1S +  0), bf0, zero4);
    a0 = MFMA(LDF(s_w1p, o1 + 0*16*K1S + 32), bf1, a0);
    a0 = MFMA(LDF(s_w1p, o1 + 0*16*K1S + 64), bf2, a0);
    a0 = MFMA(LDF(s_w1p, o1 + 0*16*K1S + 96), bf3, a0);
    f32x4 a1 = MFMA(LDF(s_w1p, o1 + 1*16*K1S +  0), bf0, zero4);
    a1 = MFMA(LDF(s_w1p, o1 + 1*16*K1S + 32), bf1, a1);
    a1 = MFMA(LDF(s_w1p, o1 + 1*16*K1S + 64), bf2, a1);
    a1 = MFMA(LDF(s_w1p, o1 + 1*16*K1S + 96), bf3, a1);
#pragma unroll
    for (int r = 0; r < 4; ++r) { a0[r] = fmaxf(a0[r], 0.f); a1[r] = fmaxf(a1[r], 0.f); }
    const bf16x8 hb0 = pack8(a0, a1);
    f32x4 a2 = MFMA(LDF(s_w1p, o1 + 2*16*K1S +  0), bf0, zero4);
    a2 = MFMA(LDF(s_w1p, o1 + 2*16*K1S + 32), bf1, a2);
    a2 = MFMA(LDF(s_w1p, o1 + 2*16*K1S + 64), bf2, a2);
    a2 = MFMA(LDF(s_w1p, o1 + 2*16*K1S + 96), bf3, a2);
    f32x4 a3 = MFMA(LDF(s_w1p, o1 + 3*16*K1S +  0), bf0, zero4);
    a3 = MFMA(LDF(s_w1p, o1 + 3*16*K1S + 32), bf1, a3);
    a3 = MFMA(LDF(s_w1p, o1 + 3*16*K1S + 64), bf2, a3);
    a3 = MFMA(LDF(s_w1p, o1 + 3*16*K1S + 96), bf3, a3);
#pragma unroll
    for (int r = 0; r < 4; ++r) { a2[r] = fmaxf(a2[r], 0.f); a3[r] = fmaxf(a3[r], 0.f); }
    const bf16x8 hb1 = pack8(a2, a3);

    // ---- L2: m^T tiles ----
    f32x4 c0 = MFMA(LDF(s_w2p, o2 + 0*16*K2S +  0), hb0, zero4);
    c0 = MFMA(LDF(s_w2p, o2 + 0*16*K2S + 32), hb1, c0);
    f32x4 c1 = MFMA(LDF(s_w2p, o2 + 1*16*K2S +  0), hb0, zero4);
    c1 = MFMA(LDF(s_w2p, o2 + 1*16*K2S + 32), hb1, c1);
#pragma unroll
    for (int r = 0; r < 4; ++r) {
      c0[r] = (c0[r] + b2r[0*4+r]) * mask_f;  msacc[0*4+r] += c0[r];
      c1[r] = (c1[r] + b2r[1*4+r]) * mask_f;  msacc[1*4+r] += c1[r];
    }
    const bf16x8 mb0 = pack8(c0, c1);
    f32x4 c2 = MFMA(LDF(s_w2p, o2 + 2*16*K2S +  0), hb0, zero4);
    c2 = MFMA(LDF(s_w2p, o2 + 2*16*K2S + 32), hb1, c2);
    f32x4 c3 = MFMA(LDF(s_w2p, o2 + 3*16*K2S +  0), hb0, zero4);
    c3 = MFMA(LDF(s_w2p, o2 + 3*16*K2S + 32), hb1, c3);
#pragma unroll
    for (int r = 0; r < 4; ++r) {
      c2[r] = (c2[r] + b2r[2*4+r]) * mask_f;  msacc[2*4+r] += c2[r];
      c3[r] = (c3[r] + b2r[3*4+r]) * mask_f;  msacc[3*4+r] += c3[r];
    }
    const bf16x8 mb1 = pack8(c2, c3);

    // ---- tr1: th^T tiles (tw1 A-frags from LDS) ----
    f32x4 d0 = MFMA(LDF(s_tw1p, o2 + 0*16*K2S +  0), mb0, zero4);
    d0 = MFMA(LDF(s_tw1p, o2 + 0*16*K2S + 32), mb1, d0);
    f32x4 d1 = MFMA(LDF(s_tw1p, o2 + 1*16*K2S +  0), mb0, zero4);
    d1 = MFMA(LDF(s_tw1p, o2 + 1*16*K2S + 32), mb1, d1);
#pragma unroll
    for (int r = 0; r < 4; ++r) {
      d0[r] = fmaxf(d0[r] + tb1r[0*4+r], 0.f);
      d1[r] = fmaxf(d1[r] + tb1r[1*4+r], 0.f);
    }
    const bf16x8 thb0 = pack8(d0, d1);
    f32x4 d2f = MFMA(LDF(s_tw1p, o2 + 2*16*K2S +  0), mb0, zero4);
    d2f = MFMA(LDF(s_tw1p, o2 + 2*16*K2S + 32), mb1, d2f);
    f32x4 d3 = MFMA(LDF(s_tw1p, o2 + 3*16*K2S +  0), mb0, zero4);
    d3 = MFMA(LDF(s_tw1p, o2 + 3*16*K2S + 32), mb1, d3);
#pragma unroll
    for (int r = 0; r < 4; ++r) {
      d2f[r] = fmaxf(d2f[r] + tb1r[2*4+r], 0.f);
      d3[r]  = fmaxf(d3[r]  + tb1r[3*4+r], 0.f);
    }
    const bf16x8 thb1 = pack8(d2f, d3);

    // ---- dx: 2 MFMAs with tw2^T (rows 0..2 = dims) ----
    f32x4 dacc = MFMA(tw2f[0], thb0, zero4);
    dacc = MFMA(tw2f[1], thb1, dacc);

    if (lg == 0) {
      const float dx0 = (dacc[0] + tb2r0) * mask_f;
      const float dx1 = (dacc[1] + tb2r1) * mask_f;
      const float dx2 = (dacc[2] + tb2r2) * mask_f;
      const float4 qn = *(const float4*)&s_qn[j*4];
      const float w = qn.x, ux = qn.y, uy = qn.z, uz = qn.w;
      const float r0 = 2.f*(uy*dx2 - uz*dx1);
      const float r1 = 2.f*(uz*dx0 - ux*dx2);
      const float r2 = 2.f*(ux*dx1 - uy*dx0);
      gx0 += dx0 + w*r0 + (uy*r2 - uz*r1);
      gx1 += dx1 + w*r1 + (uz*r0 - ux*r2);
      gx2 += dx2 + w*r2 + (ux*r1 - uy*r0);
    }
  }

  // ---- epilogue: msum (reduce over the 16 l15 lanes), gdx ----
#pragma unroll
  for (int v = 0; v < 16; ++v) {
    float x = msacc[v];
    x += __shfl_xor(x, 1); x += __shfl_xor(x, 2);
    x += __shfl_xor(x, 4); x += __shfl_xor(x, 8);
    if (l15 == 0) {
      const int n2 = (v>>3)*32 + lg*8 + ((v>>2)&1)*4 + (v&3);
      atomicAdd(&s_msum[n2], x);
    }
  }
  {
    float v0 = (lg == 0) ? gx0 : 0.f;
    float v1 = (lg == 0) ? gx1 : 0.f;
    float v2 = (lg == 0) ? gx2 : 0.f;
#pragma unroll
    for (int sft = 1; sft < 64; sft <<= 1) {
      v0 += __shfl_xor(v0, sft); v1 += __shfl_xor(v1, sft); v2 += __shfl_xor(v2, sft);
    }
    if (lane == 0) { atomicAdd(&s_gdx[0], v0); atomicAdd(&s_gdx[1], v1); atomicAdd(&s_gdx[2], v2); }
  }
  __syncthreads();
  if (tid < 64) msum_ws[(b*NN + i)*64 + tid] = s_msum[tid];
  if (tid >= 64 && tid < 67) gdx_ws[(b*NN + i)*3 + (tid - 64)] = s_gdx[tid - 64];
}

// One block (1 wave) per (b, i): o, dq->upd_q, upd_x, torsions.
__global__ __launch_bounds__(64) void egnn_node_kernel(
    const float* __restrict__ frames_q, const float* __restrict__ frames_x,
    const float* __restrict__ h,
    const int* __restrict__ node_mask, const int* __restrict__ pocket_mask,
    const float* __restrict__ fw1, const float* __restrict__ fb1,
    const float* __restrict__ fw2, const float* __restrict__ fb2,
    const float* __restrict__ qw1, const float* __restrict__ qb1,
    const float* __restrict__ qw2, const float* __restrict__ qb2,
    const float* __restrict__ tow1, const float* __restrict__ tob1,
    const float* __restrict__ tow2, const float* __restrict__ tob2,
    const float* __restrict__ msum_ws, const float* __restrict__ gdx_ws,
    float* __restrict__ out)
{
  const int t  = threadIdx.x;
  const int bi = blockIdx.x;
  const int b = bi / NN, i = bi % NN;
  __shared__ float s_h[64], s_ms[64], s_hid[64], s_tmp[16];

  s_h[t]  = h[(b*NN+i)*HH + t];
  s_ms[t] = msum_ws[(b*NN+i)*64 + t];

  int cnt = 0;
  for (int k = t; k < NN; k += 64) cnt += (node_mask[b*NN+k] != 0);
  for (int k = t; k < PP; k += 64) cnt += (pocket_mask[b*PP+k] != 0);
  cnt += __shfl_xor(cnt,1); cnt += __shfl_xor(cnt,2); cnt += __shfl_xor(cnt,4);
  cnt += __shfl_xor(cnt,8); cnt += __shfl_xor(cnt,16); cnt += __shfl_xor(cnt,32);
  const float n_nb = (float)(cnt - 1);

  __syncthreads();
  float a = fb1[t];
  for (int k = 0; k < 64; ++k) a = fmaf(s_h[k],  fw1[k*64 + t], a);
  for (int k = 0; k < 64; ++k) a = fmaf(s_ms[k], fw1[(64+k)*64 + t], a);
  s_hid[t] = fmaxf(a, 0.f);
  __syncthreads();
  float ov = fb2[t];
  for (int k = 0; k < 64; ++k) ov = fmaf(s_hid[k], fw2[k*64 + t], ov);
  out[O_OFF + (b*NN+i)*64 + t] = ov;

  __syncthreads();
  float aq = qb1[t];
  for (int k = 0; k < 64; ++k) aq = fmaf(s_ms[k], qw1[k*64 + t], aq);
  s_hid[t] = fmaxf(aq, 0.f);
  __syncthreads();
  if (t < 4) {
    float d = qb2[t];
    for (int k = 0; k < 64; ++k) d = fmaf(s_hid[k], qw2[k*4 + t], d);
    s_tmp[t] = d;
  }
  __syncthreads();
  if (t == 0) {
    const int mi = node_mask[b*NN+i];
    float d0,d1,d2,d3;
    if (mi) { d0=s_tmp[0]; d1=s_tmp[1]; d2=s_tmp[2]; d3=s_tmp[3]; }
    else    { d0=1.f; d1=0.f; d2=0.f; d3=0.f; }
    float nrm = fmaxf(sqrtf(d0*d0+d1*d1+d2*d2+d3*d3), 1e-12f);
    d0/=nrm; d1/=nrm; d2/=nrm; d3/=nrm;
    const float q0=frames_q[(b*NN+i)*4+0], q1=frames_q[(b*NN+i)*4+1],
                q2=frames_q[(b*NN+i)*4+2], q3=frames_q[(b*NN+i)*4+3];
    float u0 = q0*d0 - q1*d1 - q2*d2 - q3*d3;
    float u1 = q0*d1 + q1*d0 + q2*d3 - q3*d2;
    float u2 = q0*d2 - q1*d3 + q2*d0 + q3*d1;
    float u3 = q0*d3 + q1*d2 - q2*d1 + q3*d0;
    if (!mi) { u0=1.f; u1=0.f; u2=0.f; u3=0.f; }
    float nrm2 = fmaxf(sqrtf(u0*u0+u1*u1+u2*u2+u3*u3), 1e-12f);
    out[(b*NN+i)*4+0]=u0/nrm2; out[(b*NN+i)*4+1]=u1/nrm2;
    out[(b*NN+i)*4+2]=u2/nrm2; out[(b*NN+i)*4+3]=u3/nrm2;
  }
  if (t < 3) {
    out[X_OFF + (b*NN+i)*3 + t] = frames_x[(b*NN+i)*3+t] + gdx_ws[(b*NN+i)*3+t] / n_nb;
  }

  __syncthreads();
  float at = tob1[t];
  for (int k = 0; k < 64; ++k) at = fmaf(s_ms[k], tow1[k*64 + t], at);
  s_hid[t] = fmaxf(at, 0.f);
  __syncthreads();
  if (t < 14) {
    float v = tob2[t];
    for (int k = 0; k < 64; ++k) v = fmaf(s_hid[k], tow2[k*14 + t], v);
    s_tmp[t] = v;
  }
  __syncthreads();
  if (t < 14) {
    const int p = t & ~1;
    const float a0 = s_tmp[p], a1 = s_tmp[p+1];
    const float nrm = fmaxf(sqrtf(a0*a0 + a1*a1), 1e-12f);
    out[T_OFF + (b*NN+i)*14 + t] = s_tmp[t] / nrm;
  }
}

extern "C" void kernel_launch(void* const* d_in, const int* in_sizes, int n_in,
                              void* d_out, int out_size, void* d_ws, size_t ws_size,
                              hipStream_t stream) {
  const float* frames_q    = (const float*)d_in[0];
  const float* frames_x    = (const float*)d_in[1];
  const float* h           = (const float*)d_in[3];
  const float* e           = (const float*)d_in[4];
  const int*   node_mask   = (const int*)d_in[5];
  const float* pocket_h    = (const float*)d_in[6];
  const float* pocket_e    = (const float*)d_in[7];
  const float* pocket_q    = (const float*)d_in[8];
  const float* pocket_x    = (const float*)d_in[9];
  const int*   pocket_mask = (const int*)d_in[10];
  const float* msg_w1 = (const float*)d_in[11];
  const float* msg_b1 = (const float*)d_in[12];
  const float* msg_w2 = (const float*)d_in[13];
  const float* msg_b2 = (const float*)d_in[14];
  const float* feat_w1 = (const float*)d_in[15];
  const float* feat_b1 = (const float*)d_in[16];
  const float* feat_w2 = (const float*)d_in[17];
  const float* feat_b2 = (const float*)d_in[18];
  const float* tr_w1 = (const float*)d_in[19];
  const float* tr_b1 = (const float*)d_in[20];
  const float* tr_w2 = (const float*)d_in[21];
  const float* tr_b2 = (const float*)d_in[22];
  const float* qu_w1 = (const float*)d_in[23];
  const float* qu_b1 = (const float*)d_in[24];
  const float* qu_w2 = (const float*)d_in[25];
  const float* qu_b2 = (const float*)d_in[26];
  const float* to_w1 = (const float*)d_in[27];
  const float* to_b1 = (const float*)d_in[28];
  const float* to_w2 = (const float*)d_in[29];
  const float* to_b2 = (const float*)d_in[30];

  float* out = (float*)d_out;
  float* msum_ws = (float*)d_ws;                 // B*N*64 floats
  float* gdx_ws  = msum_ws + BB*NN*64;           // B*N*3 floats

  egnn_edge_swapped<<<dim3(BB*NN), dim3(512), 0, stream>>>(
      frames_q, frames_x, h, e, node_mask,
      pocket_h, pocket_e, pocket_q, pocket_x, pocket_mask,
      msg_w1, msg_b1, msg_w2, msg_b2,
      tr_w1, tr_b1, tr_w2, tr_b2,
      msum_ws, gdx_ws);

  egnn_node_kernel<<<dim3(BB*NN), dim3(64), 0, stream>>>(
      frames_q, frames_x, h, node_mask, pocket_mask,
      feat_w1, feat_b1, feat_w2, feat_b2,
      qu_w1, qu_b1, qu_w2, qu_b2,
      to_w1, to_b1, to_w2, to_b2,
      msum_ws, gdx_ws, out);
}

// Round 3
// 63.834 us; speedup vs baseline: 1.5942x; 1.1264x over previous
//
#include <hip/hip_runtime.h>
#include <math.h>

#define BB 2
#define NN 384
#define PP 128
#define HH 64
#define EE 32
#define NP 512
#define K1S 136   // w1p LDS stride (bf16): 272B
#define K2S 72    // w2p/tw1p/tw2p stride: 144B

// output layout: upd_q | upd_x | upd_torsions | o  (flat, fp32)
#define X_OFF (BB*NN*4)
#define T_OFF (X_OFF + BB*NN*3)
#define O_OFF (T_OFF + BB*NN*14)

using bf16x8 = __attribute__((ext_vector_type(8))) __bf16;
using f32x4  = __attribute__((ext_vector_type(4))) float;

__device__ __forceinline__ f32x4 MFMA(bf16x8 a, bf16x8 b, f32x4 c) {
  return __builtin_amdgcn_mfma_f32_16x16x32_bf16(a, b, c, 0, 0, 0);
}
// LDS fragment read (element offset into a __bf16 array)
__device__ __forceinline__ bf16x8 LDF(const __bf16* base, int off) {
  return *(const bf16x8*)(base + off);
}
// pack two f32x4 into bf16x8
__device__ __forceinline__ bf16x8 pack8(f32x4 lo, f32x4 hi) {
  bf16x8 r;
  r[0]=(__bf16)lo[0]; r[1]=(__bf16)lo[1]; r[2]=(__bf16)lo[2]; r[3]=(__bf16)lo[3];
  r[4]=(__bf16)hi[0]; r[5]=(__bf16)hi[1]; r[6]=(__bf16)hi[2]; r[7]=(__bf16)hi[3];
  return r;
}
__device__ __forceinline__ bf16x8 pack8v(float4 lo, float4 hi) {
  bf16x8 r;
  r[0]=(__bf16)lo.x; r[1]=(__bf16)lo.y; r[2]=(__bf16)lo.z; r[3]=(__bf16)lo.w;
  r[4]=(__bf16)hi.x; r[5]=(__bf16)hi.y; r[6]=(__bf16)hi.z; r[7]=(__bf16)hi.w;
  return r;
}
// Column permutation: n(t,q) = (t>>1)*32 + (q>>2)*8 + (t&1)*4 + (q&3).
// rowpos(n) = t*16+q, the inverse: which (tile,row) holds output column n.
__device__ __forceinline__ int rowpos(int n) {
  const int t = (n>>5)*2 + ((n>>2)&1);
  const int q = ((n>>3)&3)*4 + (n&3);
  return t*16 + q;
}

// One block = one (b,i) node, 8 waves x 512 threads. Wave w handles edges
// w*64..w*64+63 in 4 strips of 16. Per-edge geometry/mask/qn precomputed by a
// prologue pass (1 thread per j) into LDS so the strip loop is only
// {h/e float4 loads -> pack -> MFMA chain with laundered LDS weight frags}.
// NOTE launch_bounds 2nd arg is BLOCKS/CU (CUDA semantics in clang): (512,4)
// forced an 8-waves/EU 64-VGPR cap -> 29 MB of scratch spills for occupancy
// that LDS (66 KB -> 2 blocks/CU) could never deliver. (512,2) = 128-reg cap.
__global__ __launch_bounds__(512, 2) void egnn_edge_swapped(
    const float* __restrict__ frames_q, const float* __restrict__ frames_x,
    const float* __restrict__ h, const float* __restrict__ e,
    const int* __restrict__ node_mask,
    const float* __restrict__ pocket_h, const float* __restrict__ pe,
    const float* __restrict__ pocket_q, const float* __restrict__ pocket_x,
    const int* __restrict__ pocket_mask,
    const float* __restrict__ w1, const float* __restrict__ b1,
    const float* __restrict__ w2, const float* __restrict__ b2,
    const float* __restrict__ tw1, const float* __restrict__ tb1,
    const float* __restrict__ tw2, const float* __restrict__ tb2,
    float* __restrict__ msum_ws, float* __restrict__ gdx_ws)
{
  __shared__ __align__(16) __bf16 s_w1p[64*K1S];   // permuted W1^T (k-dim 0..127)
  __shared__ __align__(16) __bf16 s_w2p[64*K2S];   // permuted W2^T
  __shared__ __align__(16) __bf16 s_tw1p[64*K2S];  // permuted tw1^T
  __shared__ __align__(16) __bf16 s_tw2p[16*K2S];  // tw2^T (rows 0..2 = dims)
  __shared__ __align__(16) __bf16 s_geo[NP*16 + 8]; // per-edge bf3 frag (+zero slot)
  __shared__ __align__(16) float s_qn[NP*4];       // normalized q_all
  __shared__ float s_maskf[NP];
  __shared__ float s_b2[64], s_tb1[64], s_tb2[4];
  __shared__ float s_msum[64], s_gdx[3];

  const int tid = threadIdx.x;
  const int b = blockIdx.x / NN, i = blockIdx.x % NN;

  // ---- stage permuted weights to LDS (bf16) ----
  for (int idx = tid; idx < 64*128; idx += 512) {
    const int n = idx & 63, k = idx >> 6;
    float v = 0.f;
    if      (k < 64)  v = w1[(64 + k)*64 + n];         // h_j rows
    else if (k < 96)  v = w1[(128 + (k-64))*64 + n];   // e rows
    else if (k < 105) v = w1[(160 + (k-96))*64 + n];   // geom rows (lx,lq,d2,qdot)
    s_w1p[rowpos(n)*K1S + k] = (__bf16)v;              // k==105 overwritten below
  }
  for (int idx = tid; idx < 64*64; idx += 512) {
    const int n = idx & 63, k = idx >> 6;
    s_w2p[rowpos(n)*K2S + k]  = (__bf16)w2[k*64 + n];
    s_tw1p[rowpos(n)*K2S + k] = (__bf16)tw1[k*64 + n];
  }
  for (int idx = tid; idx < 16*64; idx += 512) {
    const int row = idx >> 6, k = idx & 63;
    s_tw2p[row*K2S + k] = (__bf16)((row < 3) ? tw2[k*3 + row] : 0.f);
  }
  if (tid < 64) { s_b2[tid] = b2[tid]; s_tb1[tid] = tb1[tid]; s_msum[tid] = 0.f; }
  if (tid < 8)  s_geo[NP*16 + tid] = (__bf16)0.f;      // zero slot for lg>=2
  if (tid < 3)  { s_tb2[tid] = tb2[tid]; s_gdx[tid] = 0.f; }
  __syncthreads();

  // base_i = b1 + h_i @ W1[0:64] -> const column k=105 (feat[105] = 1.0)
  if (tid < 64) {
    const float* hi = &h[(b*NN + i)*HH];
    float a = b1[tid];
#pragma unroll 8
    for (int c = 0; c < 64; ++c) a = fmaf(hi[c], w1[c*64 + tid], a);
    s_w1p[rowpos(tid)*K1S + 105] = (__bf16)a;
  }

  // ---- per-edge geometry precompute: one thread per j ----
  {
    const int j = tid;   // 512 threads == NP edges
    const int maski = node_mask[b*NN + i];
    const float qi0 = frames_q[(b*NN+i)*4+0], qi1 = frames_q[(b*NN+i)*4+1],
                qi2 = frames_q[(b*NN+i)*4+2], qi3 = frames_q[(b*NN+i)*4+3];
    const float xi0 = frames_x[(b*NN+i)*3+0], xi1 = frames_x[(b*NN+i)*3+1],
                xi2 = frames_x[(b*NN+i)*3+2];
    float qj0,qj1,qj2,qj3, xj0,xj1,xj2; int mj;
    if (j < NN) {
      const float4 q4 = *(const float4*)&frames_q[(b*NN+j)*4];
      qj0=q4.x; qj1=q4.y; qj2=q4.z; qj3=q4.w;
      xj0=frames_x[(b*NN+j)*3+0]; xj1=frames_x[(b*NN+j)*3+1]; xj2=frames_x[(b*NN+j)*3+2];
      mj = (node_mask[b*NN+j] != 0) && (j != i);
    } else {
      const int jp = j - NN;
      const float4 q4 = *(const float4*)&pocket_q[(b*PP+jp)*4];
      qj0=q4.x; qj1=q4.y; qj2=q4.z; qj3=q4.w;
      xj0=pocket_x[(b*PP+jp)*3+0]; xj1=pocket_x[(b*PP+jp)*3+1]; xj2=pocket_x[(b*PP+jp)*3+2];
      mj = (pocket_mask[b*PP+jp] != 0);
    }
    const float v0 = xi0 - xj0, v1 = xi1 - xj1, v2 = xi2 - xj2;
    const float d2 = v0*v0 + v1*v1 + v2*v2;
    const float qdot = fabsf(qi0*qj0 + qi1*qj1 + qi2*qj2 + qi3*qj3);
    const float cw = qj0, cx = -qj1, cy = -qj2, cz = -qj3;
    const float t0 = 2.f*(cy*v2 - cz*v1);
    const float t1 = 2.f*(cz*v0 - cx*v2);
    const float t2 = 2.f*(cx*v1 - cy*v0);
    const float lx0 = v0 + cw*t0 + (cy*t2 - cz*t1);
    const float lx1 = v1 + cw*t1 + (cz*t0 - cx*t2);
    const float lx2 = v2 + cw*t2 + (cx*t1 - cy*t0);
    const float lq0 = cw*qi0 - cx*qi1 - cy*qi2 - cz*qi3;
    const float lq1 = cw*qi1 + cx*qi0 + cy*qi3 - cz*qi2;
    const float lq2 = cw*qi2 - cx*qi3 + cy*qi0 + cz*qi1;
    const float lq3 = cw*qi3 + cx*qi2 - cy*qi1 + cz*qi0;
    __bf16* g = &s_geo[j*16];
    g[0]=(__bf16)lx0; g[1]=(__bf16)lx1; g[2]=(__bf16)lx2; g[3]=(__bf16)lq0;
    g[4]=(__bf16)lq1; g[5]=(__bf16)lq2; g[6]=(__bf16)lq3; g[7]=(__bf16)d2;
    g[8]=(__bf16)qdot; g[9]=(__bf16)1.f;
    g[10]=(__bf16)0.f; g[11]=(__bf16)0.f; g[12]=(__bf16)0.f;
    g[13]=(__bf16)0.f; g[14]=(__bf16)0.f; g[15]=(__bf16)0.f;
    s_maskf[j] = (maski && mj) ? 1.f : 0.f;
    const float inv = 1.f / fmaxf(sqrtf(qj0*qj0 + qj1*qj1 + qj2*qj2 + qj3*qj3), 1e-12f);
    float4* qn = (float4*)&s_qn[j*4];
    *qn = make_float4(qj0*inv, qj1*inv, qj2*inv, qj3*inv);
  }
  __syncthreads();

  const int wv = tid >> 6, lane = tid & 63;
  const int l15 = lane & 15, lg = lane >> 4;

  // ---- per-wave register prologue (small stuff only) ----
  bf16x8 tw2f[2];
  tw2f[0] = *(const bf16x8*)&s_tw2p[l15*K2S +  0 + lg*8];
  tw2f[1] = *(const bf16x8*)&s_tw2p[l15*K2S + 32 + lg*8];

  float b2r[16], tb1r[16];
#pragma unroll
  for (int t2 = 0; t2 < 4; ++t2)
#pragma unroll
    for (int r = 0; r < 4; ++r) {
      const int n2 = (t2>>1)*32 + lg*8 + (t2&1)*4 + r;
      b2r[t2*4 + r]  = s_b2[n2];
      tb1r[t2*4 + r] = s_tb1[n2];
    }
  const float tb2r0 = s_tb2[0], tb2r1 = s_tb2[1], tb2r2 = s_tb2[2];

  float msacc[16];
#pragma unroll
  for (int v = 0; v < 16; ++v) msacc[v] = 0.f;
  float gx0 = 0.f, gx1 = 0.f, gx2 = 0.f;

  const int o1base = l15*K1S + lg*8;   // W1 frag base (element offset)
  const int o2base = l15*K2S + lg*8;   // W2 / tw1 frag base

#pragma unroll 2
  for (int s = 0; s < 4; ++s) {
    // per-iteration launder: keeps the weight-fragment ds_reads inside the
    // loop (LICM would otherwise hoist 24 bf16x8 frags back into registers
    // and blow the VGPR budget -> scratch spills)
    int o1 = o1base; asm volatile("" : "+v"(o1));
    int o2 = o2base; asm volatile("" : "+v"(o2));

    const int jbase = wv*64 + s*16;
    const int j = jbase + l15;
    const bool isn = (jbase < NN);      // uniform per strip
    const float *hj, *ej;
    if (isn) {
      hj = &h[(b*NN + j)*HH];
      ej = &e[((b*NN + i)*NN + j)*EE];
    } else {
      const int jp = j - NN;
      hj = &pocket_h[(b*PP + jp)*HH];
      ej = &pe[((b*NN + i)*PP + jp)*EE];
    }
    const float mask_f = s_maskf[j];

    const float4 h0 = *(const float4*)&hj[lg*8];
    const float4 h1 = *(const float4*)&hj[lg*8 + 4];
    const float4 h2 = *(const float4*)&hj[32 + lg*8];
    const float4 h3 = *(const float4*)&hj[32 + lg*8 + 4];
    const float4 e0 = *(const float4*)&ej[lg*8];
    const float4 e1 = *(const float4*)&ej[lg*8 + 4];

    // B-fragments of L1: feat^T, k-slices of 32
    const bf16x8 bf0 = pack8v(h0, h1);
    const bf16x8 bf1 = pack8v(h2, h3);
    const bf16x8 bf2 = pack8v(e0, e1);
    // geometry fragment: precomputed; lg>=2 lanes read the shared zero slot
    const bf16x8 bf3 = *(const bf16x8*)&s_geo[(lg < 2) ? (j*16 + lg*8) : NP*16];

    const f32x4 zero4 = {0.f, 0.f, 0.f, 0.f};
    // ---- L1: hidden^T tiles (output cols permuted by n(t,q)) ----
    f32x4 a0 = MFMA(LDF(s_w1p, o1 + 0*16*K1S +  0), bf0, zero4);
    a0 = MFMA(LDF(s_w1p, o1 + 0*16*K1S + 32), bf1, a0);
    a0 = MFMA(LDF(s_w1p, o1 + 0*16*K1S + 64), bf2, a0);
    a0 = MFMA(LDF(s_w1p, o1 + 0*16*K1S + 96), bf3, a0);
    f32x4 a1 = MFMA(LDF(s_w1p, o1 + 1*16*K1S +  0), bf0, zero4);
    a1 = MFMA(LDF(s_w1p, o1 + 1*16*K1S + 32), bf1, a1);
    a1 = MFMA(LDF(s_w1p, o1 + 1*16*K1S + 64), bf2, a1);
    a1 = MFMA(LDF(s_w1p, o1 + 1*16*K1S + 96), bf3, a1);
#pragma unroll
    for (int r = 0; r < 4; ++r) { a0[r] = fmaxf(a0[r], 0.f); a1[r] = fmaxf(a1[r], 0.f); }
    const bf16x8 hb0 = pack8(a0, a1);
    f32x4 a2 = MFMA(LDF(s_w1p, o1 + 2*16*K1S +  0), bf0, zero4);
    a2 = MFMA(LDF(s_w1p, o1 + 2*16*K1S + 32), bf1, a2);
    a2 = MFMA(LDF(s_w1p, o1 + 2*16*K1S + 64), bf2, a2);
    a2 = MFMA(LDF(s_w1p, o1 + 2*16*K1S + 96), bf3, a2);
    f32x4 a3 = MFMA(LDF(s_w1p, o1 + 3*16*K1S +  0), bf0, zero4);
    a3 = MFMA(LDF(s_w1p, o1 + 3*16*K1S + 32), bf1, a3);
    a3 = MFMA(LDF(s_w1p, o1 + 3*16*K1S + 64), bf2, a3);
    a3 = MFMA(LDF(s_w1p, o1 + 3*16*K1S + 96), bf3, a3);
#pragma unroll
    for (int r = 0; r < 4; ++r) { a2[r] = fmaxf(a2[r], 0.f); a3[r] = fmaxf(a3[r], 0.f); }
    const bf16x8 hb1 = pack8(a2, a3);

    // ---- L2: m^T tiles ----
    f32x4 c0 = MFMA(LDF(s_w2p, o2 + 0*16*K2S +  0), hb0, zero4);
    c0 = MFMA(LDF(s_w2p, o2 + 0*16*K2S + 32), hb1, c0);
    f32x4 c1 = MFMA(LDF(s_w2p, o2 + 1*16*K2S +  0), hb0, zero4);
    c1 = MFMA(LDF(s_w2p, o2 + 1*16*K2S + 32), hb1, c1);
#pragma unroll
    for (int r = 0; r < 4; ++r) {
      c0[r] = (c0[r] + b2r[0*4+r]) * mask_f;  msacc[0*4+r] += c0[r];
      c1[r] = (c1[r] + b2r[1*4+r]) * mask_f;  msacc[1*4+r] += c1[r];
    }
    const bf16x8 mb0 = pack8(c0, c1);
    f32x4 c2 = MFMA(LDF(s_w2p, o2 + 2*16*K2S +  0), hb0, zero4);
    c2 = MFMA(LDF(s_w2p, o2 + 2*16*K2S + 32), hb1, c2);
    f32x4 c3 = MFMA(LDF(s_w2p, o2 + 3*16*K2S +  0), hb0, zero4);
    c3 = MFMA(LDF(s_w2p, o2 + 3*16*K2S + 32), hb1, c3);
#pragma unroll
    for (int r = 0; r < 4; ++r) {
      c2[r] = (c2[r] + b2r[2*4+r]) * mask_f;  msacc[2*4+r] += c2[r];
      c3[r] = (c3[r] + b2r[3*4+r]) * mask_f;  msacc[3*4+r] += c3[r];
    }
    const bf16x8 mb1 = pack8(c2, c3);

    // ---- tr1: th^T tiles (tw1 A-frags from LDS) ----
    f32x4 d0 = MFMA(LDF(s_tw1p, o2 + 0*16*K2S +  0), mb0, zero4);
    d0 = MFMA(LDF(s_tw1p, o2 + 0*16*K2S + 32), mb1, d0);
    f32x4 d1 = MFMA(LDF(s_tw1p, o2 + 1*16*K2S +  0), mb0, zero4);
    d1 = MFMA(LDF(s_tw1p, o2 + 1*16*K2S + 32), mb1, d1);
#pragma unroll
    for (int r = 0; r < 4; ++r) {
      d0[r] = fmaxf(d0[r] + tb1r[0*4+r], 0.f);
      d1[r] = fmaxf(d1[r] + tb1r[1*4+r], 0.f);
    }
    const bf16x8 thb0 = pack8(d0, d1);
    f32x4 d2f = MFMA(LDF(s_tw1p, o2 + 2*16*K2S +  0), mb0, zero4);
    d2f = MFMA(LDF(s_tw1p, o2 + 2*16*K2S + 32), mb1, d2f);
    f32x4 d3 = MFMA(LDF(s_tw1p, o2 + 3*16*K2S +  0), mb0, zero4);
    d3 = MFMA(LDF(s_tw1p, o2 + 3*16*K2S + 32), mb1, d3);
#pragma unroll
    for (int r = 0; r < 4; ++r) {
      d2f[r] = fmaxf(d2f[r] + tb1r[2*4+r], 0.f);
      d3[r]  = fmaxf(d3[r]  + tb1r[3*4+r], 0.f);
    }
    const bf16x8 thb1 = pack8(d2f, d3);

    // ---- dx: 2 MFMAs with tw2^T (rows 0..2 = dims) ----
    f32x4 dacc = MFMA(tw2f[0], thb0, zero4);
    dacc = MFMA(tw2f[1], thb1, dacc);

    if (lg == 0) {
      const float dx0 = (dacc[0] + tb2r0) * mask_f;
      const float dx1 = (dacc[1] + tb2r1) * mask_f;
      const float dx2 = (dacc[2] + tb2r2) * mask_f;
      const float4 qn = *(const float4*)&s_qn[j*4];
      const float w = qn.x, ux = qn.y, uy = qn.z, uz = qn.w;
      const float r0 = 2.f*(uy*dx2 - uz*dx1);
      const float r1 = 2.f*(uz*dx0 - ux*dx2);
      const float r2 = 2.f*(ux*dx1 - uy*dx0);
      gx0 += dx0 + w*r0 + (uy*r2 - uz*r1);
      gx1 += dx1 + w*r1 + (uz*r0 - ux*r2);
      gx2 += dx2 + w*r2 + (ux*r1 - uy*r0);
    }
  }

  // ---- epilogue: msum (reduce over the 16 l15 lanes), gdx ----
#pragma unroll
  for (int v = 0; v < 16; ++v) {
    float x = msacc[v];
    x += __shfl_xor(x, 1); x += __shfl_xor(x, 2);
    x += __shfl_xor(x, 4); x += __shfl_xor(x, 8);
    if (l15 == 0) {
      const int n2 = (v>>3)*32 + lg*8 + ((v>>2)&1)*4 + (v&3);
      atomicAdd(&s_msum[n2], x);
    }
  }
  {
    float v0 = (lg == 0) ? gx0 : 0.f;
    float v1 = (lg == 0) ? gx1 : 0.f;
    float v2 = (lg == 0) ? gx2 : 0.f;
#pragma unroll
    for (int sft = 1; sft < 64; sft <<= 1) {
      v0 += __shfl_xor(v0, sft); v1 += __shfl_xor(v1, sft); v2 += __shfl_xor(v2, sft);
    }
    if (lane == 0) { atomicAdd(&s_gdx[0], v0); atomicAdd(&s_gdx[1], v1); atomicAdd(&s_gdx[2], v2); }
  }
  __syncthreads();
  if (tid < 64) msum_ws[(b*NN + i)*64 + tid] = s_msum[tid];
  if (tid >= 64 && tid < 67) gdx_ws[(b*NN + i)*3 + (tid - 64)] = s_gdx[tid - 64];
}

// One block (1 wave) per (b, i): o, dq->upd_q, upd_x, torsions.
__global__ __launch_bounds__(64) void egnn_node_kernel(
    const float* __restrict__ frames_q, const float* __restrict__ frames_x,
    const float* __restrict__ h,
    const int* __restrict__ node_mask, const int* __restrict__ pocket_mask,
    const float* __restrict__ fw1, const float* __restrict__ fb1,
    const float* __restrict__ fw2, const float* __restrict__ fb2,
    const float* __restrict__ qw1, const float* __restrict__ qb1,
    const float* __restrict__ qw2, const float* __restrict__ qb2,
    const float* __restrict__ tow1, const float* __restrict__ tob1,
    const float* __restrict__ tow2, const float* __restrict__ tob2,
    const float* __restrict__ msum_ws, const float* __restrict__ gdx_ws,
    float* __restrict__ out)
{
  const int t  = threadIdx.x;
  const int bi = blockIdx.x;
  const int b = bi / NN, i = bi % NN;
  __shared__ float s_h[64], s_ms[64], s_hid[64], s_tmp[16];

  s_h[t]  = h[(b*NN+i)*HH + t];
  s_ms[t] = msum_ws[(b*NN+i)*64 + t];

  int cnt = 0;
  for (int k = t; k < NN; k += 64) cnt += (node_mask[b*NN+k] != 0);
  for (int k = t; k < PP; k += 64) cnt += (pocket_mask[b*PP+k] != 0);
  cnt += __shfl_xor(cnt,1); cnt += __shfl_xor(cnt,2); cnt += __shfl_xor(cnt,4);
  cnt += __shfl_xor(cnt,8); cnt += __shfl_xor(cnt,16); cnt += __shfl_xor(cnt,32);
  const float n_nb = (float)(cnt - 1);

  __syncthreads();
  float a = fb1[t];
  for (int k = 0; k < 64; ++k) a = fmaf(s_h[k],  fw1[k*64 + t], a);
  for (int k = 0; k < 64; ++k) a = fmaf(s_ms[k], fw1[(64+k)*64 + t], a);
  s_hid[t] = fmaxf(a, 0.f);
  __syncthreads();
  float ov = fb2[t];
  for (int k = 0; k < 64; ++k) ov = fmaf(s_hid[k], fw2[k*64 + t], ov);
  out[O_OFF + (b*NN+i)*64 + t] = ov;

  __syncthreads();
  float aq = qb1[t];
  for (int k = 0; k < 64; ++k) aq = fmaf(s_ms[k], qw1[k*64 + t], aq);
  s_hid[t] = fmaxf(aq, 0.f);
  __syncthreads();
  if (t < 4) {
    float d = qb2[t];
    for (int k = 0; k < 64; ++k) d = fmaf(s_hid[k], qw2[k*4 + t], d);
    s_tmp[t] = d;
  }
  __syncthreads();
  if (t == 0) {
    const int mi = node_mask[b*NN+i];
    float d0,d1,d2,d3;
    if (mi) { d0=s_tmp[0]; d1=s_tmp[1]; d2=s_tmp[2]; d3=s_tmp[3]; }
    else    { d0=1.f; d1=0.f; d2=0.f; d3=0.f; }
    float nrm = fmaxf(sqrtf(d0*d0+d1*d1+d2*d2+d3*d3), 1e-12f);
    d0/=nrm; d1/=nrm; d2/=nrm; d3/=nrm;
    const float q0=frames_q[(b*NN+i)*4+0], q1=frames_q[(b*NN+i)*4+1],
                q2=frames_q[(b*NN+i)*4+2], q3=frames_q[(b*NN+i)*4+3];
    float u0 = q0*d0 - q1*d1 - q2*d2 - q3*d3;
    float u1 = q0*d1 + q1*d0 + q2*d3 - q3*d2;
    float u2 = q0*d2 - q1*d3 + q2*d0 + q3*d1;
    float u3 = q0*d3 + q1*d2 - q2*d1 + q3*d0;
    if (!mi) { u0=1.f; u1=0.f; u2=0.f; u3=0.f; }
    float nrm2 = fmaxf(sqrtf(u0*u0+u1*u1+u2*u2+u3*u3), 1e-12f);
    out[(b*NN+i)*4+0]=u0/nrm2; out[(b*NN+i)*4+1]=u1/nrm2;
    out[(b*NN+i)*4+2]=u2/nrm2; out[(b*NN+i)*4+3]=u3/nrm2;
  }
  if (t < 3) {
    out[X_OFF + (b*NN+i)*3 + t] = frames_x[(b*NN+i)*3+t] + gdx_ws[(b*NN+i)*3+t] / n_nb;
  }

  __syncthreads();
  float at = tob1[t];
  for (int k = 0; k < 64; ++k) at = fmaf(s_ms[k], tow1[k*64 + t], at);
  s_hid[t] = fmaxf(at, 0.f);
  __syncthreads();
  if (t < 14) {
    float v = tob2[t];
    for (int k = 0; k < 64; ++k) v = fmaf(s_hid[k], tow2[k*14 + t], v);
    s_tmp[t] = v;
  }
  __syncthreads();
  if (t < 14) {
    const int p = t & ~1;
    const float a0 = s_tmp[p], a1 = s_tmp[p+1];
    const float nrm = fmaxf(sqrtf(a0*a0 + a1*a1), 1e-12f);
    out[T_OFF + (b*NN+i)*14 + t] = s_tmp[t] / nrm;
  }
}

extern "C" void kernel_launch(void* const* d_in, const int* in_sizes, int n_in,
                              void* d_out, int out_size, void* d_ws, size_t ws_size,
                              hipStream_t stream) {
  const float* frames_q    = (const float*)d_in[0];
  const float* frames_x    = (const float*)d_in[1];
  const float* h           = (const float*)d_in[3];
  const float* e           = (const float*)d_in[4];
  const int*   node_mask   = (const int*)d_in[5];
  const float* pocket_h    = (const float*)d_in[6];
  const float* pocket_e    = (const float*)d_in[7];
  const float* pocket_q    = (const float*)d_in[8];
  const float* pocket_x    = (const float*)d_in[9];
  const int*   pocket_mask = (const int*)d_in[10];
  const float* msg_w1 = (const float*)d_in[11];
  const float* msg_b1 = (const float*)d_in[12];
  const float* msg_w2 = (const float*)d_in[13];
  const float* msg_b2 = (const float*)d_in[14];
  const float* feat_w1 = (const float*)d_in[15];
  const float* feat_b1 = (const float*)d_in[16];
  const float* feat_w2 = (const float*)d_in[17];
  const float* feat_b2 = (const float*)d_in[18];
  const float* tr_w1 = (const float*)d_in[19];
  const float* tr_b1 = (const float*)d_in[20];
  const float* tr_w2 = (const float*)d_in[21];
  const float* tr_b2 = (const float*)d_in[22];
  const float* qu_w1 = (const float*)d_in[23];
  const float* qu_b1 = (const float*)d_in[24];
  const float* qu_w2 = (const float*)d_in[25];
  const float* qu_b2 = (const float*)d_in[26];
  const float* to_w1 = (const float*)d_in[27];
  const float* to_b1 = (const float*)d_in[28];
  const float* to_w2 = (const float*)d_in[29];
  const float* to_b2 = (const float*)d_in[30];

  float* out = (float*)d_out;
  float* msum_ws = (float*)d_ws;                 // B*N*64 floats
  float* gdx_ws  = msum_ws + BB*NN*64;           // B*N*3 floats

  egnn_edge_swapped<<<dim3(BB*NN), dim3(512), 0, stream>>>(
      frames_q, frames_x, h, e, node_mask,
      pocket_h, pocket_e, pocket_q, pocket_x, pocket_mask,
      msg_w1, msg_b1, msg_w2, msg_b2,
      tr_w1, tr_b1, tr_w2, tr_b2,
      msum_ws, gdx_ws);

  egnn_node_kernel<<<dim3(BB*NN), dim3(64), 0, stream>>>(
      frames_q, frames_x, h, node_mask, pocket_mask,
      feat_w1, feat_b1, feat_w2, feat_b2,
      qu_w1, qu_b1, qu_w2, qu_b2,
      to_w1, to_b1, to_w2, to_b2,
      msum_ws, gdx_ws, out);
}